// Round 1
// baseline (862.643 us; speedup 1.0000x reference)
//
#include <hip/hip_runtime.h>

#define NN 8192
#define DD 112
#define KK 6            // k+1 entries per row
#define NCHUNK 16
#define CHUNKSZ (NN / NCHUNK)   // 512
#define F1 32
#define F2 8

// ---------------- workspace layout (float offsets) ----------------
// h:  NN*DD            conv features
// xn: NN*DD            normalized rows
// candv: NN*NCHUNK*KK  partial top-k values   (region reused for Z1/ACC1/HH1/Z2/ACC2 after merge)
// candi: NN*NCHUNK*KK  partial top-k indices
// topv/topi: NN*KK     final top-k
// rowsum, colsum, dinv: NN each
// Gg: 18 floats (G[2][8], g[2])
static const size_t OFF_H     = 0;
static const size_t OFF_XN    = OFF_H + (size_t)NN * DD;
static const size_t OFF_CANDV = OFF_XN + (size_t)NN * DD;
static const size_t OFF_CANDI = OFF_CANDV + (size_t)NN * NCHUNK * KK;
static const size_t OFF_TOPV  = OFF_CANDI + (size_t)NN * NCHUNK * KK;
static const size_t OFF_TOPI  = OFF_TOPV + (size_t)NN * KK;
static const size_t OFF_ROWS  = OFF_TOPI + (size_t)NN * KK;
static const size_t OFF_COLS  = OFF_ROWS + (size_t)NN;
static const size_t OFF_DINV  = OFF_COLS + (size_t)NN;
static const size_t OFF_GG    = OFF_DINV + (size_t)NN;
// GCN temporaries alias the (already-consumed) candidate region:
static const size_t OFF_Z1    = OFF_CANDV;                      // NN*F1
static const size_t OFF_ACC1  = OFF_Z1 + (size_t)NN * F1;       // NN*F1
static const size_t OFF_HH1   = OFF_ACC1 + (size_t)NN * F1;     // NN*F1
static const size_t OFF_Z2    = OFF_HH1 + (size_t)NN * F1;      // NN*F2
static const size_t OFF_ACC2  = OFF_Z2 + (size_t)NN * F2;       // NN*F2

__device__ __forceinline__ float lrelu(float x) { return x >= 0.f ? x : 0.01f * x; }

// ---------------- K0: fold attention+classifier into G (2x8), g (2) ----------------
__global__ void k_consts(const float* __restrict__ ipw, const float* __restrict__ ipb,
                         const float* __restrict__ opw, const float* __restrict__ opb,
                         const float* __restrict__ clsw, const float* __restrict__ clsb,
                         float* __restrict__ Gg) {
    if (blockIdx.x != 0 || threadIdx.x != 0) return;
    float M[8][8], cv[8];
#pragma unroll
    for (int c = 0; c < 8; ++c) {
        float s = opb[c];
#pragma unroll
        for (int a = 0; a < 8; ++a) s = fmaf(opw[c * 8 + a], ipb[16 + a], s);
        cv[c] = s;
#pragma unroll
        for (int b = 0; b < 8; ++b) {
            float m = 0.f;
#pragma unroll
            for (int a = 0; a < 8; ++a) m = fmaf(opw[c * 8 + a], ipw[(16 + a) * 8 + b], m);
            M[c][b] = m;
        }
    }
#pragma unroll
    for (int o = 0; o < 2; ++o) {
#pragma unroll
        for (int e = 0; e < 8; ++e) {
            float s = clsw[o * 16 + e];
#pragma unroll
            for (int f = 0; f < 8; ++f) s = fmaf(clsw[o * 16 + 8 + f], M[f][e], s);
            Gg[o * 8 + e] = s;
        }
        float s = clsb[o];
#pragma unroll
        for (int f = 0; f < 8; ++f) s = fmaf(clsw[o * 16 + 8 + f], cv[f], s);
        Gg[16 + o] = s;
    }
}

// ---------------- K1: conv1d (k=3, 4 ch) + leaky + row norm; zero colsum ----------------
__global__ __launch_bounds__(256) void k_conv(const float* __restrict__ xraw,
                                              const float* __restrict__ cw,
                                              const float* __restrict__ cb,
                                              float* __restrict__ h, float* __restrict__ xn,
                                              float* __restrict__ colsum) {
    int i = blockIdx.x * 256 + threadIdx.x;
    float x[30];
#pragma unroll
    for (int t = 0; t < 30; ++t) x[t] = xraw[i * 30 + t];
    float hh[112];
    float ss = 0.f;
#pragma unroll
    for (int c = 0; c < 4; ++c) {
        float w0 = cw[c * 3 + 0], w1 = cw[c * 3 + 1], w2 = cw[c * 3 + 2], b = cb[c];
#pragma unroll
        for (int t = 0; t < 28; ++t) {
            float u = x[t] * w0 + x[t + 1] * w1 + x[t + 2] * w2 + b;
            u = lrelu(u);
            hh[c * 28 + t] = u;
            ss = fmaf(u, u, ss);
        }
    }
    float inv = 1.f / fmaxf(sqrtf(ss), 1e-12f);
#pragma unroll
    for (int t = 0; t < 112; ++t) {
        h[i * 112 + t] = hh[t];
        xn[i * 112 + t] = hh[t] * inv;
    }
    colsum[i] = 0.f;
}

// ---------------- K2: streaming per-row top-6 over a j-chunk ----------------
__global__ __launch_bounds__(256) void k_knn(const float* __restrict__ xn,
                                             float* __restrict__ candv,
                                             int* __restrict__ candi) {
    int row = blockIdx.x * 256 + threadIdx.x;
    int chunk = blockIdx.y;
    const float4* __restrict__ xr = reinterpret_cast<const float4*>(xn + (size_t)row * DD);
    float4 r[28];
#pragma unroll
    for (int t = 0; t < 28; ++t) r[t] = xr[t];
    float v[KK];
    int ix[KK];
#pragma unroll
    for (int t = 0; t < KK; ++t) { v[t] = -3.0e38f; ix[t] = -1; }
    int j0 = chunk * CHUNKSZ;
    for (int jj = 0; jj < CHUNKSZ; ++jj) {
        int j = j0 + jj;  // wave-uniform -> scalar loads below
        const float4* __restrict__ xj = reinterpret_cast<const float4*>(xn + (size_t)j * DD);
        float a0 = 0.f, a1 = 0.f, a2 = 0.f, a3 = 0.f;
#pragma unroll
        for (int t = 0; t < 28; ++t) {
            float4 b = xj[t];
            a0 = fmaf(r[t].x, b.x, a0);
            a1 = fmaf(r[t].y, b.y, a1);
            a2 = fmaf(r[t].z, b.z, a2);
            a3 = fmaf(r[t].w, b.w, a3);
        }
        float dot = (a0 + a1) + (a2 + a3);
        if (dot > v[KK - 1]) {
            v[KK - 1] = dot;
            ix[KK - 1] = j;
#pragma unroll
            for (int p = KK - 1; p > 0; --p) {
                if (v[p] > v[p - 1]) {
                    float tv = v[p]; v[p] = v[p - 1]; v[p - 1] = tv;
                    int ti = ix[p]; ix[p] = ix[p - 1]; ix[p - 1] = ti;
                }
            }
        }
    }
    size_t base = (size_t)row * (NCHUNK * KK) + (size_t)chunk * KK;
#pragma unroll
    for (int t = 0; t < KK; ++t) {
        candv[base + t] = v[t];
        candi[base + t] = ix[t];
    }
}

// ---------------- K3: merge 16x6 candidates -> top-6; rowsum; atomic colsum ----------------
__global__ __launch_bounds__(256) void k_merge(const float* __restrict__ cv,
                                               const int* __restrict__ ci,
                                               float* __restrict__ tv, int* __restrict__ ti,
                                               float* __restrict__ rowsum,
                                               float* __restrict__ colsum) {
    int i = blockIdx.x * 256 + threadIdx.x;
    const float* cvr = cv + (size_t)i * (NCHUNK * KK);
    const int* cir = ci + (size_t)i * (NCHUNK * KK);
    float sv[KK];
    int si[KK];
#pragma unroll
    for (int r = 0; r < KK; ++r) {
        float bv = -3.0e38f;
        int bi = 0x7fffffff;
        for (int c = 0; c < NCHUNK * KK; ++c) {
            float vv = cvr[c];
            int ii = cir[c];
            if (ii < 0) continue;
            bool used = false;
#pragma unroll
            for (int u = 0; u < KK; ++u)
                if (u < r && si[u] == ii) used = true;
            if (!used && (vv > bv || (vv == bv && ii < bi))) { bv = vv; bi = ii; }
        }
        sv[r] = bv;
        si[r] = bi;
    }
    float rs = 0.f;
#pragma unroll
    for (int r = 0; r < KK; ++r) {
        rs += sv[r];
        tv[(size_t)i * KK + r] = sv[r];
        ti[(size_t)i * KK + r] = si[r];
        atomicAdd(&colsum[si[r]], sv[r]);
    }
    rowsum[i] = rs;
}

// ---------------- K4: deg -> d^-1/2 ----------------
__global__ __launch_bounds__(256) void k_deg(const float* __restrict__ rowsum,
                                             const float* __restrict__ colsum,
                                             float* __restrict__ dinv) {
    int i = blockIdx.x * 256 + threadIdx.x;
    float deg = 0.5f * (rowsum[i] + colsum[i]) + 1.0f;  // +1 for the added identity
    dinv[i] = 1.0f / sqrtf(deg);
}

// ---------------- K5/K8: Z = dinv * (X @ W); zero acc ----------------
template <int DIN, int FOUT>
__global__ __launch_bounds__(256) void k_z(const float* __restrict__ x,
                                           const float* __restrict__ w,
                                           const float* __restrict__ dinv,
                                           float* __restrict__ z, float* __restrict__ acc) {
    int t = blockIdx.x * 256 + threadIdx.x;
    int i = t / FOUT, f = t % FOUT;
    float s = 0.f;
    for (int d = 0; d < DIN; ++d) s = fmaf(x[(size_t)i * DIN + d], w[d * FOUT + f], s);
    z[t] = dinv[i] * s;
    acc[t] = 0.f;
}

// ---------------- K6/K9: scatter transpose edges: acc[j] += 0.5*val*Z[i] ----------------
template <int FOUT>
__global__ __launch_bounds__(256) void k_scat(const float* __restrict__ z,
                                              const float* __restrict__ tv,
                                              const int* __restrict__ ti,
                                              float* __restrict__ acc) {
    int t = blockIdx.x * 256 + threadIdx.x;
    int i = t / FOUT, f = t % FOUT;
    float zi = z[t];
#pragma unroll
    for (int r = 0; r < KK; ++r) {
        float val = tv[(size_t)i * KK + r];
        int j = ti[(size_t)i * KK + r];
        atomicAdd(&acc[(size_t)j * FOUT + f], 0.5f * val * zi);
    }
}

// ---------------- K7: H1 = leaky(dinv*(Z + 0.5*gather + acc) + b) ----------------
template <int FOUT>
__global__ __launch_bounds__(256) void k_fin(const float* __restrict__ z,
                                             const float* __restrict__ tv,
                                             const int* __restrict__ ti,
                                             const float* __restrict__ acc,
                                             const float* __restrict__ dinv,
                                             const float* __restrict__ b,
                                             float* __restrict__ out) {
    int t = blockIdx.x * 256 + threadIdx.x;
    int i = t / FOUT, f = t % FOUT;
    float s = z[t] + acc[t];
#pragma unroll
    for (int r = 0; r < KK; ++r) {
        float val = tv[(size_t)i * KK + r];
        int j = ti[(size_t)i * KK + r];
        s = fmaf(0.5f * val, z[(size_t)j * FOUT + f], s);
    }
    out[t] = lrelu(fmaf(dinv[i], s, 0.f) + b[f]);
}

// ---------------- K10: layer-2 finalize + folded attention/classifier ----------------
__global__ __launch_bounds__(256) void k_out(const float* __restrict__ z2,
                                             const float* __restrict__ tv,
                                             const int* __restrict__ ti,
                                             const float* __restrict__ acc2,
                                             const float* __restrict__ dinv,
                                             const float* __restrict__ b2,
                                             const float* __restrict__ Gg,
                                             float* __restrict__ out) {
    int i = blockIdx.x * 256 + threadIdx.x;
    float hr[8];
#pragma unroll
    for (int f = 0; f < 8; ++f) {
        float s = z2[(size_t)i * 8 + f] + acc2[(size_t)i * 8 + f];
#pragma unroll
        for (int r = 0; r < KK; ++r) {
            float val = tv[(size_t)i * KK + r];
            int j = ti[(size_t)i * KK + r];
            s = fmaf(0.5f * val, z2[(size_t)j * 8 + f], s);
        }
        hr[f] = lrelu(dinv[i] * s + b2[f]);
    }
    float o0 = Gg[16], o1 = Gg[17];
#pragma unroll
    for (int e = 0; e < 8; ++e) {
        o0 = fmaf(Gg[e], hr[e], o0);
        o1 = fmaf(Gg[8 + e], hr[e], o1);
    }
    out[(size_t)i * 2 + 0] = o0;
    out[(size_t)i * 2 + 1] = o1;
}

extern "C" void kernel_launch(void* const* d_in, const int* in_sizes, int n_in,
                              void* d_out, int out_size, void* d_ws, size_t ws_size,
                              hipStream_t stream) {
    const float* xraw = (const float*)d_in[0];
    const float* convw = (const float*)d_in[2];
    const float* convb = (const float*)d_in[3];
    const float* rw1 = (const float*)d_in[4];
    const float* rb1 = (const float*)d_in[5];
    const float* rw2 = (const float*)d_in[6];
    const float* rb2 = (const float*)d_in[7];
    const float* ipw = (const float*)d_in[12];
    const float* ipb = (const float*)d_in[13];
    const float* opw = (const float*)d_in[14];
    const float* opb = (const float*)d_in[15];
    const float* clsw = (const float*)d_in[22];
    const float* clsb = (const float*)d_in[23];

    float* ws = (float*)d_ws;
    float* h = ws + OFF_H;
    float* xn = ws + OFF_XN;
    float* candv = ws + OFF_CANDV;
    int* candi = (int*)(ws + OFF_CANDI);
    float* topv = ws + OFF_TOPV;
    int* topi = (int*)(ws + OFF_TOPI);
    float* rowsum = ws + OFF_ROWS;
    float* colsum = ws + OFF_COLS;
    float* dinv = ws + OFF_DINV;
    float* Gg = ws + OFF_GG;
    float* z1 = ws + OFF_Z1;
    float* acc1 = ws + OFF_ACC1;
    float* hh1 = ws + OFF_HH1;
    float* z2 = ws + OFF_Z2;
    float* acc2 = ws + OFF_ACC2;

    k_consts<<<1, 64, 0, stream>>>(ipw, ipb, opw, opb, clsw, clsb, Gg);
    k_conv<<<NN / 256, 256, 0, stream>>>(xraw, convw, convb, h, xn, colsum);
    k_knn<<<dim3(NN / 256, NCHUNK), 256, 0, stream>>>(xn, candv, candi);
    k_merge<<<NN / 256, 256, 0, stream>>>(candv, candi, topv, topi, rowsum, colsum);
    k_deg<<<NN / 256, 256, 0, stream>>>(rowsum, colsum, dinv);

    k_z<DD, F1><<<(NN * F1) / 256, 256, 0, stream>>>(h, rw1, dinv, z1, acc1);
    k_scat<F1><<<(NN * F1) / 256, 256, 0, stream>>>(z1, topv, topi, acc1);
    k_fin<F1><<<(NN * F1) / 256, 256, 0, stream>>>(z1, topv, topi, acc1, dinv, rb1, hh1);

    k_z<F1, F2><<<(NN * F2) / 256, 256, 0, stream>>>(hh1, rw2, dinv, z2, acc2);
    k_scat<F2><<<(NN * F2) / 256, 256, 0, stream>>>(z2, topv, topi, acc2);
    k_out<<<NN / 256, 256, 0, stream>>>(z2, topv, topi, acc2, dinv, rb2, Gg, (float*)d_out);
}

// Round 2
// 700.980 us; speedup vs baseline: 1.2306x; 1.2306x over previous
//
#include <hip/hip_runtime.h>

#define NN 8192
#define DD 112
#define KK 6            // k+1 entries per row
#define NCHUNK 16
#define CHUNKSZ (NN / NCHUNK)   // 512
#define TJ 64           // j-tile staged in LDS
#define F1 32
#define F2 8

// ---------------- workspace layout (float offsets) ----------------
static const size_t OFF_H     = 0;
static const size_t OFF_XN    = OFF_H + (size_t)NN * DD;
static const size_t OFF_CANDV = OFF_XN + (size_t)NN * DD;
static const size_t OFF_CANDI = OFF_CANDV + (size_t)NN * NCHUNK * KK;
static const size_t OFF_TOPV  = OFF_CANDI + (size_t)NN * NCHUNK * KK;
static const size_t OFF_TOPI  = OFF_TOPV + (size_t)NN * KK;
static const size_t OFF_ROWS  = OFF_TOPI + (size_t)NN * KK;
static const size_t OFF_COLS  = OFF_ROWS + (size_t)NN;
static const size_t OFF_DINV  = OFF_COLS + (size_t)NN;
static const size_t OFF_GG    = OFF_DINV + (size_t)NN;
// GCN temporaries alias the (already-consumed) candidate region:
static const size_t OFF_Z1    = OFF_CANDV;                      // NN*F1
static const size_t OFF_ACC1  = OFF_Z1 + (size_t)NN * F1;       // NN*F1
static const size_t OFF_HH1   = OFF_ACC1 + (size_t)NN * F1;     // NN*F1
static const size_t OFF_Z2    = OFF_HH1 + (size_t)NN * F1;      // NN*F2
static const size_t OFF_ACC2  = OFF_Z2 + (size_t)NN * F2;       // NN*F2

__device__ __forceinline__ float lrelu(float x) { return x >= 0.f ? x : 0.01f * x; }

// ---------------- K0: fold attention+classifier into G (2x8), g (2) ----------------
__global__ void k_consts(const float* __restrict__ ipw, const float* __restrict__ ipb,
                         const float* __restrict__ opw, const float* __restrict__ opb,
                         const float* __restrict__ clsw, const float* __restrict__ clsb,
                         float* __restrict__ Gg) {
    if (blockIdx.x != 0 || threadIdx.x != 0) return;
    float M[8][8], cv[8];
#pragma unroll
    for (int c = 0; c < 8; ++c) {
        float s = opb[c];
#pragma unroll
        for (int a = 0; a < 8; ++a) s = fmaf(opw[c * 8 + a], ipb[16 + a], s);
        cv[c] = s;
#pragma unroll
        for (int b = 0; b < 8; ++b) {
            float m = 0.f;
#pragma unroll
            for (int a = 0; a < 8; ++a) m = fmaf(opw[c * 8 + a], ipw[(16 + a) * 8 + b], m);
            M[c][b] = m;
        }
    }
#pragma unroll
    for (int o = 0; o < 2; ++o) {
#pragma unroll
        for (int e = 0; e < 8; ++e) {
            float s = clsw[o * 16 + e];
#pragma unroll
            for (int f = 0; f < 8; ++f) s = fmaf(clsw[o * 16 + 8 + f], M[f][e], s);
            Gg[o * 8 + e] = s;
        }
        float s = clsb[o];
#pragma unroll
        for (int f = 0; f < 8; ++f) s = fmaf(clsw[o * 16 + 8 + f], cv[f], s);
        Gg[16 + o] = s;
    }
}

// ---------------- K1: conv1d (k=3, 4 ch) + leaky + row norm; zero colsum ----------------
__global__ __launch_bounds__(256) void k_conv(const float* __restrict__ xraw,
                                              const float* __restrict__ cw,
                                              const float* __restrict__ cb,
                                              float* __restrict__ h, float* __restrict__ xn,
                                              float* __restrict__ colsum) {
    int i = blockIdx.x * 256 + threadIdx.x;
    float x[30];
#pragma unroll
    for (int t = 0; t < 30; ++t) x[t] = xraw[i * 30 + t];
    float hh[112];
    float ss = 0.f;
#pragma unroll
    for (int c = 0; c < 4; ++c) {
        float w0 = cw[c * 3 + 0], w1 = cw[c * 3 + 1], w2 = cw[c * 3 + 2], b = cb[c];
#pragma unroll
        for (int t = 0; t < 28; ++t) {
            float u = x[t] * w0 + x[t + 1] * w1 + x[t + 2] * w2 + b;
            u = lrelu(u);
            hh[c * 28 + t] = u;
            ss = fmaf(u, u, ss);
        }
    }
    float inv = 1.f / fmaxf(sqrtf(ss), 1e-12f);
#pragma unroll
    for (int t = 0; t < 112; ++t) {
        h[i * 112 + t] = hh[t];
        xn[i * 112 + t] = hh[t] * inv;
    }
    colsum[i] = 0.f;
}

// ---------------- K2: streaming per-row top-6; row in VGPRs, j-tile in LDS ----------------
__global__ __launch_bounds__(256, 2) void k_knn(const float* __restrict__ xn,
                                                float* __restrict__ candv,
                                                int* __restrict__ candi) {
    __shared__ float4 tile[TJ * 28];   // 64 j-rows x 112 floats = 28 KB
    int row = blockIdx.x * 256 + threadIdx.x;
    int chunk = blockIdx.y;
    const float4* __restrict__ xr = reinterpret_cast<const float4*>(xn) + (size_t)row * 28;
    float4 r[28];
#pragma unroll
    for (int t = 0; t < 28; ++t) r[t] = xr[t];
    float v[KK];
    int ix[KK];
#pragma unroll
    for (int t = 0; t < KK; ++t) { v[t] = -3.0e38f; ix[t] = -1; }
    int j0 = chunk * CHUNKSZ;

    for (int tt = 0; tt < CHUNKSZ / TJ; ++tt) {
        // cooperative stage: 64 rows * 28 float4 = 1792 float4, 7 per thread, linear
        const float4* __restrict__ src =
            reinterpret_cast<const float4*>(xn) + (size_t)(j0 + tt * TJ) * 28;
#pragma unroll
        for (int k = 0; k < 7; ++k) {
            int e = threadIdx.x + k * 256;
            tile[e] = src[e];
        }
        __syncthreads();
#pragma unroll 4
        for (int jj = 0; jj < TJ; ++jj) {
            const float4* __restrict__ xj = &tile[jj * 28];
            float a0 = 0.f, a1 = 0.f, a2 = 0.f, a3 = 0.f;
#pragma unroll
            for (int t = 0; t < 28; ++t) {
                float4 b = xj[t];
                a0 = fmaf(r[t].x, b.x, a0);
                a1 = fmaf(r[t].y, b.y, a1);
                a2 = fmaf(r[t].z, b.z, a2);
                a3 = fmaf(r[t].w, b.w, a3);
            }
            float dot = (a0 + a1) + (a2 + a3);
            int j = j0 + tt * TJ + jj;
            if (dot > v[KK - 1]) {
                v[KK - 1] = dot;
                ix[KK - 1] = j;
#pragma unroll
                for (int p = KK - 1; p > 0; --p) {
                    if (v[p] > v[p - 1]) {
                        float tv = v[p]; v[p] = v[p - 1]; v[p - 1] = tv;
                        int ti = ix[p]; ix[p] = ix[p - 1]; ix[p - 1] = ti;
                    }
                }
            }
        }
        __syncthreads();
    }

    size_t base = (size_t)row * (NCHUNK * KK) + (size_t)chunk * KK;
#pragma unroll
    for (int t = 0; t < KK; ++t) {
        candv[base + t] = v[t];
        candi[base + t] = ix[t];
    }
}

// ---------------- K3: merge 16x6 candidates -> top-6; rowsum; atomic colsum ----------------
__global__ __launch_bounds__(256) void k_merge(const float* __restrict__ cv,
                                               const int* __restrict__ ci,
                                               float* __restrict__ tv, int* __restrict__ ti,
                                               float* __restrict__ rowsum,
                                               float* __restrict__ colsum) {
    int i = blockIdx.x * 256 + threadIdx.x;
    const float* cvr = cv + (size_t)i * (NCHUNK * KK);
    const int* cir = ci + (size_t)i * (NCHUNK * KK);
    float sv[KK];
    int si[KK];
#pragma unroll
    for (int r = 0; r < KK; ++r) {
        float bv = -3.0e38f;
        int bi = 0x7fffffff;
        for (int c = 0; c < NCHUNK * KK; ++c) {
            float vv = cvr[c];
            int ii = cir[c];
            if (ii < 0) continue;
            bool used = false;
#pragma unroll
            for (int u = 0; u < KK; ++u)
                if (u < r && si[u] == ii) used = true;
            if (!used && (vv > bv || (vv == bv && ii < bi))) { bv = vv; bi = ii; }
        }
        sv[r] = bv;
        si[r] = bi;
    }
    float rs = 0.f;
#pragma unroll
    for (int r = 0; r < KK; ++r) {
        rs += sv[r];
        tv[(size_t)i * KK + r] = sv[r];
        ti[(size_t)i * KK + r] = si[r];
        atomicAdd(&colsum[si[r]], sv[r]);
    }
    rowsum[i] = rs;
}

// ---------------- K4: deg -> d^-1/2; zero acc1/acc2 ----------------
__global__ __launch_bounds__(256) void k_degzero(const float* __restrict__ rowsum,
                                                 const float* __restrict__ colsum,
                                                 float* __restrict__ dinv,
                                                 float* __restrict__ acc1,
                                                 float* __restrict__ acc2) {
    int t = blockIdx.x * 256 + threadIdx.x;           // grid covers NN*F1
    acc1[t] = 0.f;
    if (t < NN * F2) acc2[t] = 0.f;
    if (t < NN) {
        float deg = 0.5f * (rowsum[t] + colsum[t]) + 1.0f;  // +1 for identity
        dinv[t] = 1.0f / sqrtf(deg);
    }
}

// ---------------- K5/K8: Z = dinv*(X@W), then scatter transpose edges ----------------
template <int DIN, int FOUT>
__global__ __launch_bounds__(256) void k_zscat(const float* __restrict__ x,
                                               const float* __restrict__ w,
                                               const float* __restrict__ dinv,
                                               const float* __restrict__ tv,
                                               const int* __restrict__ ti,
                                               float* __restrict__ z,
                                               float* __restrict__ acc) {
    int t = blockIdx.x * 256 + threadIdx.x;
    int i = t / FOUT, f = t % FOUT;
    float s = 0.f;
    for (int d = 0; d < DIN; ++d) s = fmaf(x[(size_t)i * DIN + d], w[d * FOUT + f], s);
    float zi = dinv[i] * s;
    z[t] = zi;
#pragma unroll
    for (int r = 0; r < KK; ++r) {
        float val = tv[(size_t)i * KK + r];
        int j = ti[(size_t)i * KK + r];
        atomicAdd(&acc[(size_t)j * FOUT + f], 0.5f * val * zi);
    }
}

// ---------------- K7: H1 = leaky(dinv*(Z + 0.5*gather + acc) + b) ----------------
template <int FOUT>
__global__ __launch_bounds__(256) void k_fin(const float* __restrict__ z,
                                             const float* __restrict__ tv,
                                             const int* __restrict__ ti,
                                             const float* __restrict__ acc,
                                             const float* __restrict__ dinv,
                                             const float* __restrict__ b,
                                             float* __restrict__ out) {
    int t = blockIdx.x * 256 + threadIdx.x;
    int i = t / FOUT, f = t % FOUT;
    float s = z[t] + acc[t];
#pragma unroll
    for (int r = 0; r < KK; ++r) {
        float val = tv[(size_t)i * KK + r];
        int j = ti[(size_t)i * KK + r];
        s = fmaf(0.5f * val, z[(size_t)j * FOUT + f], s);
    }
    out[t] = lrelu(fmaf(dinv[i], s, 0.f) + b[f]);
}

// ---------------- K10: layer-2 finalize + folded attention/classifier ----------------
__global__ __launch_bounds__(256) void k_out(const float* __restrict__ z2,
                                             const float* __restrict__ tv,
                                             const int* __restrict__ ti,
                                             const float* __restrict__ acc2,
                                             const float* __restrict__ dinv,
                                             const float* __restrict__ b2,
                                             const float* __restrict__ Gg,
                                             float* __restrict__ out) {
    int i = blockIdx.x * 256 + threadIdx.x;
    float hr[8];
#pragma unroll
    for (int f = 0; f < 8; ++f) {
        float s = z2[(size_t)i * 8 + f] + acc2[(size_t)i * 8 + f];
#pragma unroll
        for (int r = 0; r < KK; ++r) {
            float val = tv[(size_t)i * KK + r];
            int j = ti[(size_t)i * KK + r];
            s = fmaf(0.5f * val, z2[(size_t)j * 8 + f], s);
        }
        hr[f] = lrelu(dinv[i] * s + b2[f]);
    }
    float o0 = Gg[16], o1 = Gg[17];
#pragma unroll
    for (int e = 0; e < 8; ++e) {
        o0 = fmaf(Gg[e], hr[e], o0);
        o1 = fmaf(Gg[8 + e], hr[e], o1);
    }
    out[(size_t)i * 2 + 0] = o0;
    out[(size_t)i * 2 + 1] = o1;
}

extern "C" void kernel_launch(void* const* d_in, const int* in_sizes, int n_in,
                              void* d_out, int out_size, void* d_ws, size_t ws_size,
                              hipStream_t stream) {
    const float* xraw = (const float*)d_in[0];
    const float* convw = (const float*)d_in[2];
    const float* convb = (const float*)d_in[3];
    const float* rw1 = (const float*)d_in[4];
    const float* rb1 = (const float*)d_in[5];
    const float* rw2 = (const float*)d_in[6];
    const float* rb2 = (const float*)d_in[7];
    const float* ipw = (const float*)d_in[12];
    const float* ipb = (const float*)d_in[13];
    const float* opw = (const float*)d_in[14];
    const float* opb = (const float*)d_in[15];
    const float* clsw = (const float*)d_in[22];
    const float* clsb = (const float*)d_in[23];

    float* ws = (float*)d_ws;
    float* h = ws + OFF_H;
    float* xn = ws + OFF_XN;
    float* candv = ws + OFF_CANDV;
    int* candi = (int*)(ws + OFF_CANDI);
    float* topv = ws + OFF_TOPV;
    int* topi = (int*)(ws + OFF_TOPI);
    float* rowsum = ws + OFF_ROWS;
    float* colsum = ws + OFF_COLS;
    float* dinv = ws + OFF_DINV;
    float* Gg = ws + OFF_GG;
    float* z1 = ws + OFF_Z1;
    float* acc1 = ws + OFF_ACC1;
    float* hh1 = ws + OFF_HH1;
    float* z2 = ws + OFF_Z2;
    float* acc2 = ws + OFF_ACC2;

    k_consts<<<1, 64, 0, stream>>>(ipw, ipb, opw, opb, clsw, clsb, Gg);
    k_conv<<<NN / 256, 256, 0, stream>>>(xraw, convw, convb, h, xn, colsum);
    k_knn<<<dim3(NN / 256, NCHUNK), 256, 0, stream>>>(xn, candv, candi);
    k_merge<<<NN / 256, 256, 0, stream>>>(candv, candi, topv, topi, rowsum, colsum);
    k_degzero<<<(NN * F1) / 256, 256, 0, stream>>>(rowsum, colsum, dinv, acc1, acc2);

    k_zscat<DD, F1><<<(NN * F1) / 256, 256, 0, stream>>>(h, rw1, dinv, topv, topi, z1, acc1);
    k_fin<F1><<<(NN * F1) / 256, 256, 0, stream>>>(z1, topv, topi, acc1, dinv, rb1, hh1);

    k_zscat<F1, F2><<<(NN * F2) / 256, 256, 0, stream>>>(hh1, rw2, dinv, topv, topi, z2, acc2);
    k_out<<<NN / 256, 256, 0, stream>>>(z2, topv, topi, acc2, dinv, rb2, Gg, (float*)d_out);
}